// Round 7
// baseline (883.553 us; speedup 1.0000x reference)
//
#include <hip/hip_runtime.h>
#include <hip/hip_bf16.h>
#include <stdint.h>

#define NN 100000
#define NE 3200000
#define EF 24
#define KF 536
#define KPAD 544
#define BM 128
#define NPB2 64          // nodes per bucket (b = dst>>6)
#define NBUCK2 1563      // ceil(NN/64)
#define CAPB2 2432       // mean 2047, sigma 45 -> +8.5 sigma
#define EPB2 8192        // edges per binfill block

typedef __attribute__((ext_vector_type(8))) short bf16x8;
typedef __attribute__((ext_vector_type(8))) unsigned short u16x8;
typedef __attribute__((ext_vector_type(4))) float f32x4;

__device__ __forceinline__ unsigned short f2bf(float f) {
  union { float f; unsigned int u; } v; v.f = f;
  unsigned int r = v.u + 0x7FFFu + ((v.u >> 16) & 1u);
  return (unsigned short)(r >> 16);
}

__device__ __forceinline__ void gload_lds16(const void* g, void* l) {
  __builtin_amdgcn_global_load_lds(
      (const __attribute__((address_space(1))) unsigned int*)g,
      (__attribute__((address_space(3))) unsigned int*)l, 16, 0, 0);
}

__global__ void wconv_kernel(const float* __restrict__ W, unsigned short* __restrict__ Wb) {
  int i = blockIdx.x * blockDim.x + threadIdx.x;
  if (i >= 512 * KPAD) return;
  int n = i / KPAD;
  int k = i - n * KPAD;
  float v = (k < KF) ? W[n * KF + k] : 0.0f;
  Wb[i] = f2bf(v);
}

// Pass 1: value-carrying bucket fill. Sequential m read; records carry the
// 24 feats as 12 bf16-pair dwords (48B, 16B-aligned) + id plane. LDS
// histogram + run reservation => contiguous runs, L2-merged writes.
__global__ __launch_bounds__(256) void binfill2_kernel(
    const float* __restrict__ m, const int* __restrict__ dst,
    int* __restrict__ gcnt, unsigned int* __restrict__ vals,
    int* __restrict__ ids) {
  __shared__ int hist[NBUCK2];
  __shared__ int off[NBUCK2];
  const int t = threadIdx.x;
  const int e0 = blockIdx.x * EPB2;
  for (int i = t; i < NBUCK2; i += 256) hist[i] = 0;
  __syncthreads();
  for (int i = t; i < EPB2; i += 256) {
    int e = e0 + i;
    if (e < NE) atomicAdd(&hist[dst[e] >> 6], 1);
  }
  __syncthreads();
  for (int i = t; i < NBUCK2; i += 256) {
    int hv = hist[i];
    off[i] = hv ? atomicAdd(&gcnt[i], hv) : 0;
  }
  __syncthreads();
  for (int i = t; i < EPB2; i += 256) {
    int e = e0 + i;
    if (e >= NE) continue;
    int d = dst[e];
    int b = d >> 6;
    int pos = atomicAdd(&off[b], 1);
    if (pos >= CAPB2) continue;
    size_t rec = (size_t)b * CAPB2 + pos;
    const float4* mrow = (const float4*)(m + (size_t)e * EF);
    unsigned int pk[12];
#pragma unroll
    for (int j = 0; j < 6; ++j) {
      float4 q = mrow[j];
      pk[2 * j] = (unsigned int)f2bf(q.x) | ((unsigned int)f2bf(q.y) << 16);
      pk[2 * j + 1] = (unsigned int)f2bf(q.z) | ((unsigned int)f2bf(q.w) << 16);
    }
    uint4* vp = (uint4*)(vals + rec * 12);
    vp[0] = make_uint4(pk[0], pk[1], pk[2], pk[3]);
    vp[1] = make_uint4(pk[4], pk[5], pk[6], pk[7]);
    vp[2] = make_uint4(pk[8], pk[9], pk[10], pk[11]);
    ids[rec] = d & 63;
  }
}

// Pass 2: one block per bucket; stream the bucket's records sequentially,
// accumulate into a 6KB LDS f32 accumulator via ds_add_f32, write ah*norm.
__global__ __launch_bounds__(256) void binsum2_kernel(
    const unsigned int* __restrict__ vals, const int* __restrict__ ids,
    const int* __restrict__ gcnt, const float* __restrict__ norm,
    float* __restrict__ ah) {
  __shared__ float acc[NPB2 * EF];  // 6 KB
  const int t = threadIdx.x;
  const int b = blockIdx.x;
  for (int i = t; i < NPB2 * EF; i += 256) acc[i] = 0.f;
  __syncthreads();
  int cnt = gcnt[b];
  if (cnt > CAPB2) cnt = CAPB2;
  const unsigned int* vbase = vals + (size_t)b * CAPB2 * 12;
  const int* ibase = ids + (size_t)b * CAPB2;
  for (int r = t; r < cnt; r += 256) {
    const uint4* vp = (const uint4*)(vbase + (size_t)r * 12);
    uint4 q0 = vp[0], q1 = vp[1], q2 = vp[2];
    int ln = ibase[r];
    float* ap = acc + ln * EF;
    unsigned int pk[12] = {q0.x, q0.y, q0.z, q0.w, q1.x, q1.y,
                           q1.z, q1.w, q2.x, q2.y, q2.z, q2.w};
#pragma unroll
    for (int j = 0; j < 12; ++j) {
      union { unsigned int u; float f; } lo, hi;
      lo.u = (pk[j] & 0xFFFFu) << 16;
      hi.u = pk[j] & 0xFFFF0000u;
      atomicAdd(ap + 2 * j, lo.f);
      atomicAdd(ap + 2 * j + 1, hi.f);
    }
  }
  __syncthreads();
  const int nb0 = b << 6;
  for (int i = t; i < NPB2 * EF; i += 256) {
    int ln = i / EF;
    int n = nb0 + ln;
    if (n < NN) ah[(size_t)n * EF + (i - ln * EF)] = acc[i] * norm[n];
  }
}

// Fused GEMM (x = [h | ah_scaled], W^T) + bias + LayerNorm + ReLU.
// Tile: BM=128 rows x 512 cols, 512 threads (8 waves: 2 m-groups x 4 n-groups),
// A register-prefetched one K-step ahead.  (unchanged from round 5)
__global__ __launch_bounds__(512) void gemm_ln_kernel(
    const float* __restrict__ h, const float* __restrict__ ah,
    const unsigned short* __restrict__ Wb,
    const float* __restrict__ bias, const float* __restrict__ gamma,
    const float* __restrict__ beta, float* __restrict__ out) {
  __shared__ __align__(16) unsigned short Alds[8 * 4 * 16 * 8];   // 8KB
  __shared__ __align__(16) unsigned short Blds[32 * 4 * 16 * 8];  // 32KB
  __shared__ float red[4][BM][2];
  __shared__ float stats[BM][2];

  const int t = threadIdx.x;
  const int lane = t & 63;
  const int w = t >> 6;
  const int lgrp = lane >> 4;
  const int llow = lane & 15;
  const int mg = w >> 2;  // 0..1
  const int ng = w & 3;   // 0..3
  const int blockRow = blockIdx.x * BM;

  const int am = t >> 2;   // 0..127
  const int akg = t & 3;   // 0..3 (k-group of 8)
  const int arow = blockRow + am;
  char* aldsdst = (char*)Alds + (((am >> 4) * 64 + akg * 16 + (am & 15)) * 16);

  f32x4 acc[4][8];
#pragma unroll
  for (int i = 0; i < 4; ++i)
#pragma unroll
    for (int j = 0; j < 8; ++j) acc[i][j] = (f32x4){0.f, 0.f, 0.f, 0.f};

  // A prefetch registers
  float4 ra0 = make_float4(0.f, 0.f, 0.f, 0.f), ra1 = ra0;
  if (arow < NN) {
    const float* p = h + (size_t)arow * 512 + akg * 8;
    ra0 = *(const float4*)p;
    ra1 = *(const float4*)(p + 4);
  }

  for (int kt = 0; kt < 17; ++kt) {
    // ---- stage B (Wb k-slice) via global_load_lds, fragment order ----
#pragma unroll
    for (int j = 0; j < 4; ++j) {
      int nt = j * 8 + w;
      const unsigned short* src = Wb + (nt * 16 + llow) * KPAD + kt * 32 + lgrp * 8;
      gload_lds16(src, (char*)Blds + nt * 1024);
    }
    // ---- write current A (from prefetch regs), then issue next A loads ----
    u16x8 bv;
    bv[0] = f2bf(ra0.x); bv[1] = f2bf(ra0.y); bv[2] = f2bf(ra0.z); bv[3] = f2bf(ra0.w);
    bv[4] = f2bf(ra1.x); bv[5] = f2bf(ra1.y); bv[6] = f2bf(ra1.z); bv[7] = f2bf(ra1.w);
    *(u16x8*)aldsdst = bv;

    ra0 = make_float4(0.f, 0.f, 0.f, 0.f); ra1 = ra0;
    if (kt < 16 && arow < NN) {
      if (kt < 15) {
        const float* p = h + (size_t)arow * 512 + (kt + 1) * 32 + akg * 8;
        ra0 = *(const float4*)p;
        ra1 = *(const float4*)(p + 4);
      } else if (akg < 3) {  // next step covers cols 512..535 = ah (pre-scaled)
        const float* p = ah + (size_t)arow * EF + akg * 8;
        ra0 = *(const float4*)p;
        ra1 = *(const float4*)(p + 4);
      }
    }

    __syncthreads();

    // ---- MFMA: 4 m-tiles x 8 n-tiles ----
    bf16x8 af[4];
#pragma unroll
    for (int mt = 0; mt < 4; ++mt)
      af[mt] = *(const bf16x8*)((const char*)Alds + (((mg * 4 + mt) * 64) + lgrp * 16 + llow) * 16);
#pragma unroll
    for (int j = 0; j < 8; ++j) {
      int nt = ng * 8 + j;
      bf16x8 bf = *(const bf16x8*)((const char*)Blds + ((nt * 64) + lgrp * 16 + llow) * 16);
#pragma unroll
      for (int mt = 0; mt < 4; ++mt)
        acc[mt][j] = __builtin_amdgcn_mfma_f32_16x16x32_bf16(af[mt], bf, acc[mt][j], 0, 0, 0);
    }
    __syncthreads();
  }

  // ---- epilogue: bias, LN stats, normalize, relu, store ----
  float bcol[8], gcol[8], btcol[8];
#pragma unroll
  for (int j = 0; j < 8; ++j) {
    int col = (ng * 8 + j) * 16 + llow;
    bcol[j] = bias[col];
    gcol[j] = gamma[col];
    btcol[j] = beta[col];
  }
  float s[4][4], ss[4][4];
#pragma unroll
  for (int mt = 0; mt < 4; ++mt)
#pragma unroll
    for (int r = 0; r < 4; ++r) { s[mt][r] = 0.f; ss[mt][r] = 0.f; }
#pragma unroll
  for (int mt = 0; mt < 4; ++mt)
#pragma unroll
    for (int j = 0; j < 8; ++j)
#pragma unroll
      for (int r = 0; r < 4; ++r) {
        float v = acc[mt][j][r] + bcol[j];
        acc[mt][j][r] = v;
        s[mt][r] += v;
        ss[mt][r] += v * v;
      }
#pragma unroll
  for (int off = 1; off < 16; off <<= 1) {
#pragma unroll
    for (int mt = 0; mt < 4; ++mt)
#pragma unroll
      for (int r = 0; r < 4; ++r) {
        s[mt][r] += __shfl_xor(s[mt][r], off, 64);
        ss[mt][r] += __shfl_xor(ss[mt][r], off, 64);
      }
  }
  if (llow == 0) {
#pragma unroll
    for (int mt = 0; mt < 4; ++mt)
#pragma unroll
      for (int r = 0; r < 4; ++r) {
        int lrow = (mg * 4 + mt) * 16 + lgrp * 4 + r;
        red[ng][lrow][0] = s[mt][r];
        red[ng][lrow][1] = ss[mt][r];
      }
  }
  __syncthreads();
  if (t < BM) {
    float sum = red[0][t][0] + red[1][t][0] + red[2][t][0] + red[3][t][0];
    float sq = red[0][t][1] + red[1][t][1] + red[2][t][1] + red[3][t][1];
    float mean = sum * (1.0f / 512.0f);
    float var = sq * (1.0f / 512.0f) - mean * mean;
    stats[t][0] = mean;
    stats[t][1] = rsqrtf(var + 1e-5f);
  }
  __syncthreads();
#pragma unroll
  for (int mt = 0; mt < 4; ++mt) {
#pragma unroll
    for (int r = 0; r < 4; ++r) {
      int lrow = (mg * 4 + mt) * 16 + lgrp * 4 + r;
      int grow = blockRow + lrow;
      if (grow < NN) {
        float mean = stats[lrow][0];
        float rstd = stats[lrow][1];
#pragma unroll
        for (int j = 0; j < 8; ++j) {
          int col = (ng * 8 + j) * 16 + llow;
          float v = (acc[mt][j][r] - mean) * rstd * gcol[j] + btcol[j];
          out[grow * 512 + col] = fmaxf(v, 0.0f);
        }
      }
    }
  }
}

extern "C" void kernel_launch(void* const* d_in, const int* in_sizes, int n_in,
                              void* d_out, int out_size, void* d_ws, size_t ws_size,
                              hipStream_t stream) {
  const float* h = (const float*)d_in[0];
  const float* m = (const float*)d_in[1];
  const int* dst = (const int*)d_in[2];
  const float* norm = (const float*)d_in[3];
  const float* W = (const float*)d_in[4];
  const float* b = (const float*)d_in[5];
  const float* gamma = (const float*)d_in[6];
  const float* beta = (const float*)d_in[7];
  float* out = (float*)d_out;

  // ws: ah (9.6 MB) + Wb (0.55 MB) — proven footprint.
  float* ah = (float*)d_ws;                                       // 9,600,000 B
  unsigned short* Wb = (unsigned short*)((char*)d_ws + 9600000);  // 557,056 B

  // d_out doubles as scratch (GEMM overwrites all of d_out afterwards):
  //   vals @ 0           : 1563*2432*48 = 182,411,264 B
  //   ids  @ 182,411,264 : 1563*2432*4  =  15,200,768 B
  //   gcnt @ 197,612,032 : 6,252 B            (total < 204,800,000 B)
  unsigned int* vals = (unsigned int*)d_out;
  int* ids = (int*)((char*)d_out + 182411264);
  int* gcnt = (int*)((char*)d_out + 197612032);

  hipMemsetAsync(gcnt, 0, NBUCK2 * sizeof(int), stream);
  wconv_kernel<<<(512 * KPAD + 255) / 256, 256, 0, stream>>>(W, Wb);
  binfill2_kernel<<<(NE + EPB2 - 1) / EPB2, 256, 0, stream>>>(m, dst, gcnt, vals, ids);
  binsum2_kernel<<<NBUCK2, 256, 0, stream>>>(vals, ids, gcnt, norm, ah);
  gemm_ln_kernel<<<(NN + BM - 1) / BM, 512, 0, stream>>>(h, ah, Wb, b, gamma, beta, out);
}

// Round 8
// 456.823 us; speedup vs baseline: 1.9341x; 1.9341x over previous
//
#include <hip/hip_runtime.h>
#include <hip/hip_bf16.h>
#include <stdint.h>

#define NN 100000
#define NE 3200000
#define EF 24
#define KF 536
#define KPAD 544
#define BM 128

typedef __attribute__((ext_vector_type(8))) short bf16x8;
typedef __attribute__((ext_vector_type(8))) unsigned short u16x8;
typedef __attribute__((ext_vector_type(4))) float f32x4;

__device__ __forceinline__ unsigned short f2bf(float f) {
  union { float f; unsigned int u; } v; v.f = f;
  unsigned int r = v.u + 0x7FFFu + ((v.u >> 16) & 1u);
  return (unsigned short)(r >> 16);
}

__device__ __forceinline__ void gload_lds16(const void* g, void* l) {
  __builtin_amdgcn_global_load_lds(
      (const __attribute__((address_space(1))) unsigned int*)g,
      (__attribute__((address_space(3))) unsigned int*)l, 16, 0, 0);
}

__global__ void wconv_kernel(const float* __restrict__ W, unsigned short* __restrict__ Wb) {
  int i = blockIdx.x * blockDim.x + threadIdx.x;
  if (i >= 512 * KPAD) return;
  int n = i / KPAD;
  int k = i - n * KPAD;
  float v = (k < KF) ? W[n * KF + k] : 0.0f;
  Wb[i] = f2bf(v);
}

// Segment-sum via packed-bf16 atomics (round-6 proven: 256 us).
__global__ __launch_bounds__(256) void scatter_pk_kernel(
    const float* __restrict__ m, const int* __restrict__ dst,
    unsigned int* __restrict__ acc) {  // acc: NN*12 dwords, each = 2 bf16
  int i = blockIdx.x * 256 + threadIdx.x;
  if (i >= NE * 12) return;
  int e = i / 12;
  int fp = i - e * 12;
  float2 v = *(const float2*)(m + (size_t)e * EF + fp * 2);
  unsigned int pk = ((unsigned int)f2bf(v.y) << 16) | (unsigned int)f2bf(v.x);
  unsigned int* p = acc + (size_t)dst[e] * 12 + fp;
  asm volatile("global_atomic_pk_add_bf16 %0, %1, off" :: "v"(p), "v"(pk) : "memory");
}

// ah[n][f] = acc_bf16[n][f] * norm[n]  (f32 out), fully coalesced.
__global__ __launch_bounds__(256) void reduce_pk_kernel(
    const unsigned int* __restrict__ acc, const float* __restrict__ norm,
    float* __restrict__ ah) {
  int i = blockIdx.x * 256 + threadIdx.x;  // dword index over NN*12
  if (i >= NN * 12) return;
  int n = i / 12;
  unsigned int pk = acc[i];
  float nv = norm[n];
  union { unsigned int u; float f; } lo, hi;
  lo.u = (pk & 0xFFFFu) << 16;
  hi.u = pk & 0xFFFF0000u;
  *(float2*)(ah + (size_t)i * 2) = make_float2(lo.f * nv, hi.f * nv);
}

// Fused GEMM (x = [h | ah_scaled], W^T) + bias + LayerNorm + ReLU.
// v2: double-buffered LDS (A and B), ONE barrier per K-step; B gload_lds and
// A reg-loads for step kt+1 issued BEFORE the MFMA cluster of step kt so the
// pre-barrier vmcnt drain is short (loads age across the MFMA phase).
__global__ __launch_bounds__(512) void gemm_ln_kernel(
    const float* __restrict__ h, const float* __restrict__ ah,
    const unsigned short* __restrict__ Wb,
    const float* __restrict__ bias, const float* __restrict__ gamma,
    const float* __restrict__ beta, float* __restrict__ out) {
  __shared__ __align__(16) unsigned short Alds[2][4096];   // 2 x 8KB
  __shared__ __align__(16) unsigned short Blds[2][16384];  // 2 x 32KB
  __shared__ float red[4][BM][2];
  __shared__ float stats[BM][2];

  const int t = threadIdx.x;
  const int lane = t & 63;
  const int w = t >> 6;
  const int lgrp = lane >> 4;
  const int llow = lane & 15;
  const int mg = w >> 2;  // 0..1
  const int ng = w & 3;   // 0..3
  const int blockRow = blockIdx.x * BM;

  const int am = t >> 2;   // 0..127
  const int akg = t & 3;   // 0..3 (k-group of 8)
  const int arow = blockRow + am;
  const int aoff = (((am >> 4) * 64 + akg * 16 + (am & 15)) * 16);  // byte off in A buf

  f32x4 acc[4][8];
#pragma unroll
  for (int i = 0; i < 4; ++i)
#pragma unroll
    for (int j = 0; j < 8; ++j) acc[i][j] = (f32x4){0.f, 0.f, 0.f, 0.f};

  // ---- prologue: stage step 0 into buffer 0 ----
#pragma unroll
  for (int j = 0; j < 4; ++j) {
    int nt = j * 8 + w;
    const unsigned short* src = Wb + (nt * 16 + llow) * KPAD + 0 * 32 + lgrp * 8;
    gload_lds16(src, (char*)Blds[0] + nt * 1024);
  }
  float4 ra0 = make_float4(0.f, 0.f, 0.f, 0.f), ra1 = ra0;
  if (arow < NN) {
    const float* p = h + (size_t)arow * 512 + akg * 8;
    ra0 = *(const float4*)p;
    ra1 = *(const float4*)(p + 4);
  }
  {
    u16x8 bv;
    bv[0] = f2bf(ra0.x); bv[1] = f2bf(ra0.y); bv[2] = f2bf(ra0.z); bv[3] = f2bf(ra0.w);
    bv[4] = f2bf(ra1.x); bv[5] = f2bf(ra1.y); bv[6] = f2bf(ra1.z); bv[7] = f2bf(ra1.w);
    *(u16x8*)((char*)Alds[0] + aoff) = bv;
  }
  __syncthreads();

  for (int kt = 0; kt < 17; ++kt) {
    const int cur = kt & 1;
    const int nxt = cur ^ 1;
    const bool more = (kt < 16);

    // ---- issue next-step loads FIRST (they age across the MFMA phase) ----
    if (more) {
#pragma unroll
      for (int j = 0; j < 4; ++j) {
        int nt = j * 8 + w;
        const unsigned short* src = Wb + (nt * 16 + llow) * KPAD + (kt + 1) * 32 + lgrp * 8;
        gload_lds16(src, (char*)Blds[nxt] + nt * 1024);
      }
      ra0 = make_float4(0.f, 0.f, 0.f, 0.f); ra1 = ra0;
      if (arow < NN) {
        if (kt + 1 < 16) {
          const float* p = h + (size_t)arow * 512 + (kt + 1) * 32 + akg * 8;
          ra0 = *(const float4*)p;
          ra1 = *(const float4*)(p + 4);
        } else if (akg < 3) {  // cols 512..535 = ah (pre-scaled); rest zero
          const float* p = ah + (size_t)arow * EF + akg * 8;
          ra0 = *(const float4*)p;
          ra1 = *(const float4*)(p + 4);
        }
      }
    }

    // ---- MFMA on current buffer ----
    bf16x8 af[4];
#pragma unroll
    for (int mt = 0; mt < 4; ++mt)
      af[mt] = *(const bf16x8*)((const char*)Alds[cur] +
                                (((mg * 4 + mt) * 64) + lgrp * 16 + llow) * 16);
#pragma unroll
    for (int j = 0; j < 8; ++j) {
      int nt = ng * 8 + j;
      bf16x8 bf = *(const bf16x8*)((const char*)Blds[cur] + ((nt * 64) + lgrp * 16 + llow) * 16);
#pragma unroll
      for (int mt = 0; mt < 4; ++mt)
        acc[mt][j] = __builtin_amdgcn_mfma_f32_16x16x32_bf16(af[mt], bf, acc[mt][j], 0, 0, 0);
    }

    // ---- convert + write next A (vmcnt wait on ra covered by MFMA phase) ----
    if (more) {
      u16x8 bv;
      bv[0] = f2bf(ra0.x); bv[1] = f2bf(ra0.y); bv[2] = f2bf(ra0.z); bv[3] = f2bf(ra0.w);
      bv[4] = f2bf(ra1.x); bv[5] = f2bf(ra1.y); bv[6] = f2bf(ra1.z); bv[7] = f2bf(ra1.w);
      *(u16x8*)((char*)Alds[nxt] + aoff) = bv;
    }
    __syncthreads();  // single barrier per step
  }

  // ---- epilogue: bias, LN stats, normalize, relu, store ----
  float bcol[8], gcol[8], btcol[8];
#pragma unroll
  for (int j = 0; j < 8; ++j) {
    int col = (ng * 8 + j) * 16 + llow;
    bcol[j] = bias[col];
    gcol[j] = gamma[col];
    btcol[j] = beta[col];
  }
  float s[4][4], ss[4][4];
#pragma unroll
  for (int mt = 0; mt < 4; ++mt)
#pragma unroll
    for (int r = 0; r < 4; ++r) { s[mt][r] = 0.f; ss[mt][r] = 0.f; }
#pragma unroll
  for (int mt = 0; mt < 4; ++mt)
#pragma unroll
    for (int j = 0; j < 8; ++j)
#pragma unroll
      for (int r = 0; r < 4; ++r) {
        float v = acc[mt][j][r] + bcol[j];
        acc[mt][j][r] = v;
        s[mt][r] += v;
        ss[mt][r] += v * v;
      }
#pragma unroll
  for (int off = 1; off < 16; off <<= 1) {
#pragma unroll
    for (int mt = 0; mt < 4; ++mt)
#pragma unroll
      for (int r = 0; r < 4; ++r) {
        s[mt][r] += __shfl_xor(s[mt][r], off, 64);
        ss[mt][r] += __shfl_xor(ss[mt][r], off, 64);
      }
  }
  if (llow == 0) {
#pragma unroll
    for (int mt = 0; mt < 4; ++mt)
#pragma unroll
      for (int r = 0; r < 4; ++r) {
        int lrow = (mg * 4 + mt) * 16 + lgrp * 4 + r;
        red[ng][lrow][0] = s[mt][r];
        red[ng][lrow][1] = ss[mt][r];
      }
  }
  __syncthreads();
  if (t < BM) {
    float sum = red[0][t][0] + red[1][t][0] + red[2][t][0] + red[3][t][0];
    float sq = red[0][t][1] + red[1][t][1] + red[2][t][1] + red[3][t][1];
    float mean = sum * (1.0f / 512.0f);
    float var = sq * (1.0f / 512.0f) - mean * mean;
    stats[t][0] = mean;
    stats[t][1] = rsqrtf(var + 1e-5f);
  }
  __syncthreads();
#pragma unroll
  for (int mt = 0; mt < 4; ++mt) {
#pragma unroll
    for (int r = 0; r < 4; ++r) {
      int lrow = (mg * 4 + mt) * 16 + lgrp * 4 + r;
      int grow = blockRow + lrow;
      if (grow < NN) {
        float mean = stats[lrow][0];
        float rstd = stats[lrow][1];
#pragma unroll
        for (int j = 0; j < 8; ++j) {
          int col = (ng * 8 + j) * 16 + llow;
          float v = (acc[mt][j][r] - mean) * rstd * gcol[j] + btcol[j];
          out[grow * 512 + col] = fmaxf(v, 0.0f);
        }
      }
    }
  }
}

extern "C" void kernel_launch(void* const* d_in, const int* in_sizes, int n_in,
                              void* d_out, int out_size, void* d_ws, size_t ws_size,
                              hipStream_t stream) {
  const float* h = (const float*)d_in[0];
  const float* m = (const float*)d_in[1];
  const int* dst = (const int*)d_in[2];
  const float* norm = (const float*)d_in[3];
  const float* W = (const float*)d_in[4];
  const float* b = (const float*)d_in[5];
  const float* gamma = (const float*)d_in[6];
  const float* beta = (const float*)d_in[7];
  float* out = (float*)d_out;

  // ws: ah (9.6 MB) + Wb (0.55 MB) — proven footprint.
  float* ah = (float*)d_ws;                                       // 9,600,000 B
  unsigned short* Wb = (unsigned short*)((char*)d_ws + 9600000);  // 557,056 B

  // bf16 accumulator lives in d_out (4.8 MB of 204.8 MB); GEMM overwrites all
  // of d_out afterwards.
  unsigned int* acc = (unsigned int*)d_out;  // NN*12 dwords = 4,800,000 B

  hipMemsetAsync(acc, 0, (size_t)NN * 12 * sizeof(unsigned int), stream);
  wconv_kernel<<<(512 * KPAD + 255) / 256, 256, 0, stream>>>(W, Wb);
  scatter_pk_kernel<<<(NE * 12 + 255) / 256, 256, 0, stream>>>(m, dst, acc);
  reduce_pk_kernel<<<(NN * 12 + 255) / 256, 256, 0, stream>>>(acc, norm, ah);
  gemm_ln_kernel<<<(NN + BM - 1) / BM, 512, 0, stream>>>(h, ah, Wb, b, gamma, beta, out);
}

// Round 9
// 418.503 us; speedup vs baseline: 2.1112x; 1.0916x over previous
//
#include <hip/hip_runtime.h>
#include <hip/hip_bf16.h>
#include <stdint.h>

#define NN 100000
#define NE 3200000
#define EF 24
#define KF 536
#define BM 64

typedef __attribute__((ext_vector_type(8))) short bf16x8;
typedef __attribute__((ext_vector_type(4))) float f32x4;

__device__ __forceinline__ unsigned short f2bf(float f) {
  union { float f; unsigned int u; } v; v.f = f;
  unsigned int r = v.u + 0x7FFFu + ((v.u >> 16) & 1u);
  return (unsigned short)(r >> 16);
}

__device__ __forceinline__ void gload_lds16(const void* g, void* l) {
  __builtin_amdgcn_global_load_lds(
      (const __attribute__((address_space(1))) unsigned int*)g,
      (__attribute__((address_space(3))) unsigned int*)l, 16, 0, 0);
}

// Wb_swz layout: [kt 0..16][nt 0..31][lane 0..63] x 16B. Fragment-linear:
// lane (lgrp,llow) holds B[col = nt*16+llow][k = kt*32 + lgrp*8 .. +8).
// GEMM B staging then reads contiguous 1KB per gload_lds (perfectly coalesced)
// with address = base + const + lane*16.
__global__ void wconv_kernel(const float* __restrict__ W, unsigned short* __restrict__ Wb) {
  int i = blockIdx.x * blockDim.x + threadIdx.x;  // over 17*32*64*8
  if (i >= 17 * 32 * 64 * 8) return;
  int j = i & 7;
  int lane = (i >> 3) & 63;
  int nt = (i >> 9) & 31;
  int kt = i >> 14;
  int row = nt * 16 + (lane & 15);
  int k = kt * 32 + (lane >> 4) * 8 + j;
  float v = (k < KF) ? W[row * KF + k] : 0.0f;
  Wb[i] = f2bf(v);
}

// Segment-sum via packed-bf16 atomics (proven 256 us total); split into two
// half-range dispatches so the GEMM surfaces in the profiler top-5.
__global__ __launch_bounds__(256) void scatter_pk_kernel(
    const float* __restrict__ m, const int* __restrict__ dst,
    unsigned int* __restrict__ acc, int base) {
  int i = base + blockIdx.x * 256 + threadIdx.x;
  if (i >= NE * 12) return;
  int e = i / 12;
  int fp = i - e * 12;
  float2 v = *(const float2*)(m + (size_t)e * EF + fp * 2);
  unsigned int pk = ((unsigned int)f2bf(v.y) << 16) | (unsigned int)f2bf(v.x);
  unsigned int* p = acc + (size_t)dst[e] * 12 + fp;
  asm volatile("global_atomic_pk_add_bf16 %0, %1, off" :: "v"(p), "v"(pk) : "memory");
}

// ah[n][f] = acc_bf16[n][f] * norm[n]  (f32 out), fully coalesced.
__global__ __launch_bounds__(256) void reduce_pk_kernel(
    const unsigned int* __restrict__ acc, const float* __restrict__ norm,
    float* __restrict__ ah) {
  int i = blockIdx.x * 256 + threadIdx.x;  // dword index over NN*12
  if (i >= NN * 12) return;
  int n = i / 12;
  unsigned int pk = acc[i];
  float nv = norm[n];
  union { unsigned int u; float f; } lo, hi;
  lo.u = (pk & 0xFFFFu) << 16;
  hi.u = pk & 0xFFFF0000u;
  *(float2*)(ah + (size_t)i * 2) = make_float2(lo.f * nv, hi.f * nv);
}

// Fused GEMM (x = [h | ah_scaled], W^T) + bias + LayerNorm + ReLU.
// v3: occupancy-first. BM=64, acc=64 VGPR, __launch_bounds__(512,4) pins
// <=128 VGPR -> 4 waves/SIMD = 2 blocks/CU so inter-block wave overlap hides
// barrier drains. B staged from pre-swizzled Wb (coalesced 1KB gload_lds,
// no address VALU in the loop). Single-buffered, 2 barriers/step.
__global__ __launch_bounds__(512, 4) void gemm_ln_kernel(
    const float* __restrict__ h, const float* __restrict__ ah,
    const unsigned short* __restrict__ Wb,
    const float* __restrict__ bias, const float* __restrict__ gamma,
    const float* __restrict__ beta, float* __restrict__ out) {
  __shared__ __align__(16) unsigned short Alds[4 * 4 * 16 * 8];   // 4KB
  __shared__ __align__(16) unsigned short Blds[32 * 4 * 16 * 8];  // 32KB
  __shared__ float red[4][BM][2];                                 // 2KB
  __shared__ float stats[BM][2];

  const int t = threadIdx.x;
  const int lane = t & 63;
  const int w = t >> 6;
  const int lgrp = lane >> 4;
  const int llow = lane & 15;
  const int mg = w >> 2;  // 0..1
  const int ng = w & 3;   // 0..3
  const int blockRow = blockIdx.x * BM;

  // A staging: thread -> (row am, kgroup akg, half ahalf); 4 f32 -> 4 bf16 each
  const int am = t >> 3;         // 0..63
  const int akg = (t >> 1) & 3;  // 0..3
  const int ahalf = t & 1;       // 0..1
  const int arow = blockRow + am;
  char* aldsdst = (char*)Alds + (((am >> 4) * 64 + akg * 16 + (am & 15)) * 16 + ahalf * 8);

  f32x4 acc[2][8];
#pragma unroll
  for (int i = 0; i < 2; ++i)
#pragma unroll
    for (int j = 0; j < 8; ++j) acc[i][j] = (f32x4){0.f, 0.f, 0.f, 0.f};

  // A prefetch registers (4 f32)
  float4 ra = make_float4(0.f, 0.f, 0.f, 0.f);
  if (arow < NN) ra = *(const float4*)(h + (size_t)arow * 512 + akg * 8 + ahalf * 4);

  for (int kt = 0; kt < 17; ++kt) {
    // ---- stage B(kt): 4 coalesced 1KB gload_lds from swizzled Wb ----
    {
      const unsigned short* src = Wb + ((size_t)(kt * 32 + w) * 64 + lane) * 8;
#pragma unroll
      for (int j = 0; j < 4; ++j)
        gload_lds16(src + (size_t)j * 8 * 64 * 8, (char*)Blds + (j * 8 + w) * 1024);
    }
    // ---- write A(kt) from prefetch regs; issue A(kt+1) loads ----
    {
      ushort4 bv;
      bv.x = f2bf(ra.x); bv.y = f2bf(ra.y); bv.z = f2bf(ra.z); bv.w = f2bf(ra.w);
      *(ushort4*)aldsdst = bv;
    }
    ra = make_float4(0.f, 0.f, 0.f, 0.f);
    if (kt < 16 && arow < NN) {
      if (kt < 15) {
        ra = *(const float4*)(h + (size_t)arow * 512 + (kt + 1) * 32 + akg * 8 + ahalf * 4);
      } else if (akg < 3) {  // cols 512..535 = ah (pre-scaled); 536..543 = 0
        ra = *(const float4*)(ah + (size_t)arow * EF + akg * 8 + ahalf * 4);
      }
    }
    __syncthreads();

    // ---- MFMA: 2 m-tiles x 8 n-tiles ----
    bf16x8 af0 = *(const bf16x8*)((const char*)Alds + (((mg * 2 + 0) * 64) + lane) * 16);
    bf16x8 af1 = *(const bf16x8*)((const char*)Alds + (((mg * 2 + 1) * 64) + lane) * 16);
#pragma unroll
    for (int j = 0; j < 8; ++j) {
      int nt = ng * 8 + j;
      bf16x8 bf = *(const bf16x8*)((const char*)Blds + ((nt * 64) + lane) * 16);
      acc[0][j] = __builtin_amdgcn_mfma_f32_16x16x32_bf16(af0, bf, acc[0][j], 0, 0, 0);
      acc[1][j] = __builtin_amdgcn_mfma_f32_16x16x32_bf16(af1, bf, acc[1][j], 0, 0, 0);
    }
    __syncthreads();
  }

  // ---- epilogue: bias, LN stats, normalize, relu, store ----
  float bcol[8], gcol[8], btcol[8];
#pragma unroll
  for (int j = 0; j < 8; ++j) {
    int col = (ng * 8 + j) * 16 + llow;
    bcol[j] = bias[col];
    gcol[j] = gamma[col];
    btcol[j] = beta[col];
  }
  float s[2][4], ss[2][4];
#pragma unroll
  for (int mt = 0; mt < 2; ++mt)
#pragma unroll
    for (int r = 0; r < 4; ++r) { s[mt][r] = 0.f; ss[mt][r] = 0.f; }
#pragma unroll
  for (int mt = 0; mt < 2; ++mt)
#pragma unroll
    for (int j = 0; j < 8; ++j)
#pragma unroll
      for (int r = 0; r < 4; ++r) {
        float v = acc[mt][j][r] + bcol[j];
        acc[mt][j][r] = v;
        s[mt][r] += v;
        ss[mt][r] += v * v;
      }
#pragma unroll
  for (int off = 1; off < 16; off <<= 1) {
#pragma unroll
    for (int mt = 0; mt < 2; ++mt)
#pragma unroll
      for (int r = 0; r < 4; ++r) {
        s[mt][r] += __shfl_xor(s[mt][r], off, 64);
        ss[mt][r] += __shfl_xor(ss[mt][r], off, 64);
      }
  }
  if (llow == 0) {
#pragma unroll
    for (int mt = 0; mt < 2; ++mt)
#pragma unroll
      for (int r = 0; r < 4; ++r) {
        int lrow = (mg * 2 + mt) * 16 + lgrp * 4 + r;
        red[ng][lrow][0] = s[mt][r];
        red[ng][lrow][1] = ss[mt][r];
      }
  }
  __syncthreads();
  if (t < BM) {
    float sum = red[0][t][0] + red[1][t][0] + red[2][t][0] + red[3][t][0];
    float sq = red[0][t][1] + red[1][t][1] + red[2][t][1] + red[3][t][1];
    float mean = sum * (1.0f / 512.0f);
    float var = sq * (1.0f / 512.0f) - mean * mean;
    stats[t][0] = mean;
    stats[t][1] = rsqrtf(var + 1e-5f);
  }
  __syncthreads();
#pragma unroll
  for (int mt = 0; mt < 2; ++mt) {
#pragma unroll
    for (int r = 0; r < 4; ++r) {
      int lrow = (mg * 2 + mt) * 16 + lgrp * 4 + r;
      int grow = blockRow + lrow;
      if (grow < NN) {
        float mean = stats[lrow][0];
        float rstd = stats[lrow][1];
#pragma unroll
        for (int j = 0; j < 8; ++j) {
          int col = (ng * 8 + j) * 16 + llow;
          float v = (acc[mt][j][r] - mean) * rstd * gcol[j] + btcol[j];
          out[grow * 512 + col] = fmaxf(v, 0.0f);
        }
      }
    }
  }
}

extern "C" void kernel_launch(void* const* d_in, const int* in_sizes, int n_in,
                              void* d_out, int out_size, void* d_ws, size_t ws_size,
                              hipStream_t stream) {
  const float* h = (const float*)d_in[0];
  const float* m = (const float*)d_in[1];
  const int* dst = (const int*)d_in[2];
  const float* norm = (const float*)d_in[3];
  const float* W = (const float*)d_in[4];
  const float* b = (const float*)d_in[5];
  const float* gamma = (const float*)d_in[6];
  const float* beta = (const float*)d_in[7];
  float* out = (float*)d_out;

  // ws: ah (9.6 MB) + Wb_swz (0.55 MB) — proven footprint.
  float* ah = (float*)d_ws;                                       // 9,600,000 B
  unsigned short* Wb = (unsigned short*)((char*)d_ws + 9600000);  // 557,056 B

  // bf16 accumulator lives in d_out (4.8 MB of 204.8 MB); GEMM overwrites all
  // of d_out afterwards.
  unsigned int* acc = (unsigned int*)d_out;  // NN*12 dwords

  const int HALF = NE * 12 / 2;  // 19,200,000

  hipMemsetAsync(acc, 0, (size_t)NN * 12 * sizeof(unsigned int), stream);
  wconv_kernel<<<(17 * 32 * 64 * 8 + 255) / 256, 256, 0, stream>>>(W, Wb);
  scatter_pk_kernel<<<HALF / 256, 256, 0, stream>>>(m, dst, acc, 0);
  scatter_pk_kernel<<<HALF / 256, 256, 0, stream>>>(m, dst, acc, HALF);
  reduce_pk_kernel<<<(NN * 12 + 255) / 256, 256, 0, stream>>>(acc, norm, ah);
  gemm_ln_kernel<<<(NN + BM - 1) / BM, 512, 0, stream>>>(h, ah, Wb, b, gamma, beta, out);
}